// Round 7
// baseline (272.755 us; speedup 1.0000x reference)
//
#include <hip/hip_runtime.h>
#include <math.h>

// HOG multi-scale feature extractor for 28x28 images. v7:
// LDS-pipe was the measured bottleneck (inst-count model matched 205us).
//  - phase A/img[] removed: Sobel reads x directly from global (L1-hot)
//  - phase C: wrap-alias slot => 1 ds_read2 + 1 ds_write2 per pixel/scale,
//    no clamp; owner folds slot[bins] into slot[0] afterwards
//  - phase D: single-pass, 4xBINS cell values in registers (static unroll)
//  - unified even cell stride PB=10 (2-way bank aliasing = free)
//  - epilogue unchanged: precomputed map + (mean,1/std), coalesced float4

constexpr int NPIX = 784;
constexpr int FEAT = 8296;            // 784 + 1152 + 2304 + 4056
constexpr int PB  = 10;               // unified padded cell stride
constexpr int O4P = 0;                // 49 cells  (7x7,  8 bins)
constexpr int O3P = 490;              // 81 cells  (9x9,  9 bins)
constexpr int O2P = 1300;             // 196 cells (14x14, 6 bins)
constexpr int HIST_TOT = 1300 + 1960; // 3260 floats = 13 KB
constexpr int NTASK = 269;            // 36 + 64 + 169 block-norm tasks
constexpr int NHOG = FEAT - NPIX;     // 7512 table entries
constexpr int NCELL = 49 + 81 + 196;  // 326 histogram cells

// ---- output index i in [784,8296) -> packed (task<<12)|hist_idx ----
__device__ __forceinline__ int feat_map(int i) {
    int task, h;
    if (i < 1936) {                    // h4: 36 tasks x 4q x 8 bins
        int k = i - 784;
        int t = k >> 5, r = k & 31;
        int q = r >> 3, j = r & 7;
        int by = t / 6, bx = t - by * 6;
        h = O4P + ((by + (q >> 1)) * 7 + bx + (q & 1)) * PB + j;
        task = t;
    } else if (i < 4240) {             // h3: 64 tasks x 4q x 9 bins
        int k = i - 1936;
        int t = k / 36, r = k - t * 36;
        int q = r / 9,  j = r - q * 9;
        int by = t >> 3, bx = t & 7;
        h = O3P + ((by + (q >> 1)) * 9 + bx + (q & 1)) * PB + j;
        task = 36 + t;
    } else {                           // h2: 169 tasks x 4q x 6 bins
        int k = i - 4240;
        int t = k / 24, r = k - t * 24;
        int q = r / 6,  j = r - q * 6;
        int by = t / 13, bx = t - by * 13;
        h = O2P + ((by + (q >> 1)) * 14 + bx + (q & 1)) * PB + j;
        task = 100 + t;
    }
    return (task << 12) | h;           // h < 3260 fits in 12 bits
}

__global__ __launch_bounds__(256)
void setup_kernel(const float* __restrict__ fmean,
                  const float* __restrict__ fstd,
                  float2* __restrict__ msr, int* __restrict__ map) {
    int i = blockIdx.x * 256 + threadIdx.x;
    if (i < FEAT) {
        msr[i] = make_float2(fmean[i], 1.0f / fstd[i]);
        if (i >= NPIX) map[i - NPIX] = feat_map(i);
    }
}

// branchless orientation in degrees == (atan2(gy,gx)*180/pi + 180) mod 180
__device__ __forceinline__ float orient_deg(float gy, float gx) {
    float ax = fabsf(gx), ay = fabsf(gy);
    float mn = fminf(ax, ay), mx = fmaxf(ax, ay);
    float r = __fdividef(mn, mx + 1e-37f);          // [0,1]
    float a = r * r;                                 // A&S 4.4.49, |err|<=1e-5
    float th = ((((0.0208351f * a - 0.0851330f) * a + 0.1801410f) * a
                 - 0.3302995f) * a + 0.9998660f) * r;
    th *= 57.29577951308232f;                        // rad -> deg, [0,45]
    if (ay > ax) th = 90.0f - th;                    // [0,90]
    bool neg = ((__float_as_uint(gx) ^ __float_as_uint(gy)) >> 31) != 0;
    float o = neg ? 180.0f - th : th;
    return (o >= 180.0f) ? 0.0f : o;                 // in [0,180)
}

__device__ __forceinline__ float ldx(const float* xb, int y, int x) {
    return (y >= 0 && y < 28 && x >= 0 && x < 28) ? xb[y * 28 + x] : 0.0f;
}

// one-pass L2-hys norm: 4 cells x BINS read once into registers
template <int BINS>
__device__ __forceinline__ float2 norm_task(const float* hist, int hoff,
                                            int Wc, int by, int bx) {
    int c00 = hoff + (by * Wc + bx) * PB;
    float v[4 * BINS];
    #pragma unroll
    for (int q = 0; q < 4; ++q) {
        int base = c00 + ((q >> 1) * Wc + (q & 1)) * PB;
        #pragma unroll
        for (int j = 0; j < BINS; ++j)
            v[q * BINS + j] = hist[base + j];
    }
    float s = 1e-6f;
    #pragma unroll
    for (int k = 0; k < 4 * BINS; ++k) s += v[k] * v[k];
    float ninv = 1.0f / sqrtf(s);
    float s2 = 1e-6f;
    #pragma unroll
    for (int k = 0; k < 4 * BINS; ++k) {
        float c = fminf(v[k] * ninv, 0.2f);
        s2 += c * c;
    }
    return make_float2(ninv, 1.0f / sqrtf(s2));
}

template <bool USE_TABLE>
__global__ __launch_bounds__(256, 6)
void hog_kernel(const float* __restrict__ x,
                const float* __restrict__ fmean,
                const float* __restrict__ fstd,
                const float2* __restrict__ msr,
                const int* __restrict__ map,
                float* __restrict__ out) {
    __shared__ __align__(16) float2 ma[NPIX];   // (mag, ang) per pixel
    __shared__ float hist[HIST_TOT];
    __shared__ float2 nrm[NTASK];

    const int b = blockIdx.x;
    const int tid = threadIdx.x;
    const float* xb = x + (size_t)b * NPIX;

    // ---- B: pixel-parallel Sobel (global reads) -> (mag, ang) into LDS ----
    for (int p = tid; p < NPIX; p += 256) {
        int y = p / 28, xx = p - (p / 28) * 28;
        float a00 = ldx(xb, y - 1, xx - 1);
        float a01 = ldx(xb, y - 1, xx);
        float a02 = ldx(xb, y - 1, xx + 1);
        float a10 = ldx(xb, y,     xx - 1);
        float a12 = ldx(xb, y,     xx + 1);
        float a20 = ldx(xb, y + 1, xx - 1);
        float a21 = ldx(xb, y + 1, xx);
        float a22 = ldx(xb, y + 1, xx + 1);
        float gxv = (a00 + 2.0f * a10 + a20 - a02 - 2.0f * a12 - a22) * 0.25f;
        float gyv = (a00 + 2.0f * a01 + a02 - a20 - 2.0f * a21 - a22) * 0.25f;
        float mag = sqrtf(gxv * gxv + gyv * gyv + 1e-6f);
        ma[p] = make_float2(mag, orient_deg(gyv, gxv));
    }
    __syncthreads();

    // ---- C: cell-parallel accumulation, exclusive LDS RMW w/ wrap slot ----
    for (int t = tid; t < NCELL; t += 256) {
        int base, y0, x0, ny, nx, bins;
        float invbw;                       // bins / 180
        if (t < 49) {                      // cell=4, bins=8, 4x4 px
            int cy = t / 7, cx = t - cy * 7;
            y0 = cy * 4; x0 = cx * 4; ny = 4; nx = 4;
            bins = 8; invbw = 8.0f / 180.0f;
            base = O4P + t * PB;
        } else if (t < 130) {              // cell=3, bins=9, 3-4 x 3-4 px
            int k = t - 49;
            int cy = k / 9, cx = k - cy * 9;
            y0 = cy * 3; x0 = cx * 3;
            ny = (cy == 8) ? 4 : 3; nx = (cx == 8) ? 4 : 3;
            bins = 9; invbw = 9.0f / 180.0f;
            base = O3P + k * PB;
        } else {                           // cell=2, bins=6, 2x2 px
            int k = t - 130;
            int cy = k / 14, cx = k - cy * 14;
            y0 = cy * 2; x0 = cx * 2; ny = 2; nx = 2;
            bins = 6; invbw = 6.0f / 180.0f;
            base = O2P + k * PB;
        }
        // zero own slots incl. wrap slot (exclusive owner, no barrier)
        for (int j = 0; j <= bins; ++j) hist[base + j] = 0.0f;
        for (int iy = 0; iy < ny; ++iy) {
            int row = (y0 + iy) * 28 + x0;
            for (int ix = 0; ix < nx; ++ix) {
                float2 m = ma[row + ix];
                float tb = m.y * invbw;            // in [0, bins)
                int b0 = (int)tb;
                float frac = tb - (float)b0;
                float w1 = m.x * frac;
                float w0 = m.x - w1;
                int a = base + b0;                 // b0+1 == bins -> wrap slot
                float h0 = hist[a];
                float h1 = hist[a + 1];            // ds_read2_b32
                hist[a]     = h0 + w0;
                hist[a + 1] = h1 + w1;             // ds_write2_b32
            }
        }
        hist[base] += hist[base + bins];           // fold wrap slot into bin 0
    }
    __syncthreads();

    // ---- D: one-pass per-task L2-hys norm factors (registers) ----
    for (int t = tid; t < NTASK; t += 256) {
        float2 r;
        if (t < 36) {
            int by = t / 6, bx = t - (t / 6) * 6;
            r = norm_task<8>(hist, O4P, 7, by, bx);
        } else if (t < 100) {
            int k = t - 36;
            r = norm_task<9>(hist, O3P, 9, k >> 3, k & 7);
        } else {
            int k = t - 100;
            int by = k / 13, bx = k - by * 13;
            r = norm_task<6>(hist, O2P, 14, by, bx);
        }
        nrm[t] = r;
    }
    __syncthreads();

    // ---- E: epilogue, coalesced float4 writes ----
    float4* outp = reinterpret_cast<float4*>(out + (size_t)b * FEAT);

    for (int i4 = tid; i4 < NPIX / 4; i4 += 256) {
        float4 v = reinterpret_cast<const float4*>(xb)[i4];  // x re-read (L2/L3)
        float4 r;
        if (USE_TABLE) {
            const float4* msr4 = reinterpret_cast<const float4*>(msr);
            float4 p0 = msr4[i4 * 2], p1 = msr4[i4 * 2 + 1];
            r.x = (v.x - p0.x) * p0.y;  r.y = (v.y - p0.z) * p0.w;
            r.z = (v.z - p1.x) * p1.y;  r.w = (v.w - p1.z) * p1.w;
        } else {
            int i = i4 * 4;
            r.x = (v.x - fmean[i])     / fstd[i];
            r.y = (v.y - fmean[i + 1]) / fstd[i + 1];
            r.z = (v.z - fmean[i + 2]) / fstd[i + 2];
            r.w = (v.w - fmean[i + 3]) / fstd[i + 3];
        }
        outp[i4] = r;
    }

    for (int t4 = tid; t4 < NHOG / 4; t4 += 256) {
        int i4 = NPIX / 4 + t4;
        int mp[4];
        if (USE_TABLE) {
            int4 m4 = reinterpret_cast<const int4*>(map)[t4];
            mp[0] = m4.x; mp[1] = m4.y; mp[2] = m4.z; mp[3] = m4.w;
        } else {
            #pragma unroll
            for (int e = 0; e < 4; ++e) mp[e] = feat_map(i4 * 4 + e);
        }
        float vv[4];
        #pragma unroll
        for (int e = 0; e < 4; ++e) {
            int task = mp[e] >> 12, h = mp[e] & 4095;
            float2 n = nrm[task];
            vv[e] = fminf(hist[h] * n.x, 0.2f) * n.y;
        }
        float4 r;
        if (USE_TABLE) {
            const float4* msr4 = reinterpret_cast<const float4*>(msr);
            float4 p0 = msr4[i4 * 2], p1 = msr4[i4 * 2 + 1];
            r.x = (vv[0] - p0.x) * p0.y;  r.y = (vv[1] - p0.z) * p0.w;
            r.z = (vv[2] - p1.x) * p1.y;  r.w = (vv[3] - p1.z) * p1.w;
        } else {
            int i = i4 * 4;
            r.x = (vv[0] - fmean[i])     / fstd[i];
            r.y = (vv[1] - fmean[i + 1]) / fstd[i + 1];
            r.z = (vv[2] - fmean[i + 2]) / fstd[i + 2];
            r.w = (vv[3] - fmean[i + 3]) / fstd[i + 3];
        }
        outp[i4] = r;
    }
}

extern "C" void kernel_launch(void* const* d_in, const int* in_sizes, int n_in,
                              void* d_out, int out_size, void* d_ws, size_t ws_size,
                              hipStream_t stream) {
    const float* x     = (const float*)d_in[0];
    const float* fmean = (const float*)d_in[1];
    const float* fstd  = (const float*)d_in[2];
    float* out = (float*)d_out;
    int B = in_sizes[0] / NPIX;

    const size_t msr_bytes = (size_t)FEAT * sizeof(float2);   // 66368
    const size_t map_bytes = (size_t)NHOG * sizeof(int);      // 30048
    if (ws_size >= msr_bytes + map_bytes) {
        float2* msr = (float2*)d_ws;
        int* map = (int*)((char*)d_ws + msr_bytes);
        hipLaunchKernelGGL(setup_kernel, dim3((FEAT + 255) / 256), dim3(256),
                           0, stream, fmean, fstd, msr, map);
        hipLaunchKernelGGL(hog_kernel<true>, dim3(B), dim3(256), 0, stream,
                           x, fmean, fstd, msr, map, out);
    } else {
        hipLaunchKernelGGL(hog_kernel<false>, dim3(B), dim3(256), 0, stream,
                           x, fmean, fstd, nullptr, nullptr, out);
    }
}

// Round 8
// 192.152 us; speedup vs baseline: 1.4195x; 1.4195x over previous
//
#include <hip/hip_runtime.h>
#include <math.h>

// HOG multi-scale feature extractor for 28x28 images. v8:
// v6 base (img staged in LDS, streaming 2-pass norm) + targeted LDS cuts:
//  - phase C: wrap-alias slot -> adjacent-pair RMW (ds_read2/write2), WITH
//    the b0 clamp restored (v7 dropped it: cross-cell scribble when
//    ang*invbw rounds up to exactly `bins`)
//  - phase D: unified even cell stride PB=10 -> aligned float2 (ds_read_b64)
//    streaming reads, no big register arrays (v7's spill suspect reverted)
//  - hist zeroing done block-wide as float4 in phase A
//  - epilogue unchanged: precomputed map + (mean,1/std), coalesced float4

constexpr int NPIX = 784;
constexpr int FEAT = 8296;            // 784 + 1152 + 2304 + 4056
constexpr int PB  = 10;               // unified padded cell stride (even)
constexpr int O4P = 0;                // 49 cells  (7x7,  8 bins)
constexpr int O3P = 490;              // 81 cells  (9x9,  9 bins)
constexpr int O2P = 1300;             // 196 cells (14x14, 6 bins)
constexpr int HIST_TOT = 3260;        // 326 cells * 10
constexpr int NTASK = 269;            // 36 + 64 + 169 block-norm tasks
constexpr int NHOG = FEAT - NPIX;     // 7512 table entries
constexpr int NCELL = 49 + 81 + 196;  // 326 histogram cells

// ---- output index i in [784,8296) -> packed (task<<12)|hist_idx ----
__device__ __forceinline__ int feat_map(int i) {
    int task, h;
    if (i < 1936) {                    // h4: 36 tasks x 4q x 8 bins
        int k = i - 784;
        int t = k >> 5, r = k & 31;
        int q = r >> 3, j = r & 7;
        int by = t / 6, bx = t - by * 6;
        h = O4P + ((by + (q >> 1)) * 7 + bx + (q & 1)) * PB + j;
        task = t;
    } else if (i < 4240) {             // h3: 64 tasks x 4q x 9 bins
        int k = i - 1936;
        int t = k / 36, r = k - t * 36;
        int q = r / 9,  j = r - q * 9;
        int by = t >> 3, bx = t & 7;
        h = O3P + ((by + (q >> 1)) * 9 + bx + (q & 1)) * PB + j;
        task = 36 + t;
    } else {                           // h2: 169 tasks x 4q x 6 bins
        int k = i - 4240;
        int t = k / 24, r = k - t * 24;
        int q = r / 6,  j = r - q * 6;
        int by = t / 13, bx = t - by * 13;
        h = O2P + ((by + (q >> 1)) * 14 + bx + (q & 1)) * PB + j;
        task = 100 + t;
    }
    return (task << 12) | h;           // h < 3260 fits in 12 bits
}

__global__ __launch_bounds__(256)
void setup_kernel(const float* __restrict__ fmean,
                  const float* __restrict__ fstd,
                  float2* __restrict__ msr, int* __restrict__ map) {
    int i = blockIdx.x * 256 + threadIdx.x;
    if (i < FEAT) {
        msr[i] = make_float2(fmean[i], 1.0f / fstd[i]);
        if (i >= NPIX) map[i - NPIX] = feat_map(i);
    }
}

// branchless orientation in degrees == (atan2(gy,gx)*180/pi + 180) mod 180
__device__ __forceinline__ float orient_deg(float gy, float gx) {
    float ax = fabsf(gx), ay = fabsf(gy);
    float mn = fminf(ax, ay), mx = fmaxf(ax, ay);
    float r = __fdividef(mn, mx + 1e-37f);          // [0,1]
    float a = r * r;                                 // A&S 4.4.49, |err|<=1e-5
    float th = ((((0.0208351f * a - 0.0851330f) * a + 0.1801410f) * a
                 - 0.3302995f) * a + 0.9998660f) * r;
    th *= 57.29577951308232f;                        // rad -> deg, [0,45]
    if (ay > ax) th = 90.0f - th;                    // [0,90]
    bool neg = ((__float_as_uint(gx) ^ __float_as_uint(gy)) >> 31) != 0;
    float o = neg ? 180.0f - th : th;
    return (o >= 180.0f) ? 0.0f : o;                 // in [0,180)
}

__device__ __forceinline__ float ldimg(const float* img, int y, int x) {
    return (y >= 0 && y < 28 && x >= 0 && x < 28) ? img[y * 28 + x] : 0.0f;
}

// streaming 2-pass L2-hys norm, aligned float2 LDS reads (no reg arrays)
template <int BINS>
__device__ __forceinline__ float2 norm_task(const float* hist, int c00, int Wc) {
    int qb[4] = {c00, c00 + PB, c00 + Wc * PB, c00 + (Wc + 1) * PB};
    float s = 1e-6f;
    #pragma unroll
    for (int q = 0; q < 4; ++q) {
        #pragma unroll
        for (int j = 0; j < BINS / 2; ++j) {
            float2 v = *reinterpret_cast<const float2*>(&hist[qb[q] + 2 * j]);
            s += v.x * v.x + v.y * v.y;
        }
        if (BINS & 1) {
            float v = hist[qb[q] + BINS - 1];
            s += v * v;
        }
    }
    float ninv = 1.0f / sqrtf(s);
    float s2 = 1e-6f;
    #pragma unroll
    for (int q = 0; q < 4; ++q) {
        #pragma unroll
        for (int j = 0; j < BINS / 2; ++j) {
            float2 v = *reinterpret_cast<const float2*>(&hist[qb[q] + 2 * j]);
            float c0 = fminf(v.x * ninv, 0.2f);
            float c1 = fminf(v.y * ninv, 0.2f);
            s2 += c0 * c0 + c1 * c1;
        }
        if (BINS & 1) {
            float c = fminf(hist[qb[q] + BINS - 1] * ninv, 0.2f);
            s2 += c * c;
        }
    }
    return make_float2(ninv, 1.0f / sqrtf(s2));
}

template <bool USE_TABLE>
__global__ __launch_bounds__(256)
void hog_kernel(const float* __restrict__ x,
                const float* __restrict__ fmean,
                const float* __restrict__ fstd,
                const float2* __restrict__ msr,
                const int* __restrict__ map,
                float* __restrict__ out) {
    __shared__ __align__(16) float img[NPIX];
    __shared__ __align__(16) float2 ma[NPIX];   // (mag, ang) per pixel
    __shared__ __align__(16) float hist[HIST_TOT];
    __shared__ float2 nrm[NTASK];

    const int b = blockIdx.x;
    const int tid = threadIdx.x;
    const float* xb = x + (size_t)b * NPIX;

    // ---- A: load image (coalesced float4) + zero hist (float4) ----
    for (int i = tid; i < NPIX / 4; i += 256)
        reinterpret_cast<float4*>(img)[i] =
            reinterpret_cast<const float4*>(xb)[i];
    for (int i = tid; i < HIST_TOT / 4; i += 256)
        reinterpret_cast<float4*>(hist)[i] = make_float4(0.f, 0.f, 0.f, 0.f);
    __syncthreads();

    // ---- B: pixel-parallel Sobel + (mag, ang) into LDS ----
    for (int p = tid; p < NPIX; p += 256) {
        int y = p / 28, xx = p - (p / 28) * 28;
        float a00 = ldimg(img, y - 1, xx - 1);
        float a01 = ldimg(img, y - 1, xx);
        float a02 = ldimg(img, y - 1, xx + 1);
        float a10 = ldimg(img, y,     xx - 1);
        float a12 = ldimg(img, y,     xx + 1);
        float a20 = ldimg(img, y + 1, xx - 1);
        float a21 = ldimg(img, y + 1, xx);
        float a22 = ldimg(img, y + 1, xx + 1);
        float gxv = (a00 + 2.0f * a10 + a20 - a02 - 2.0f * a12 - a22) * 0.25f;
        float gyv = (a00 + 2.0f * a01 + a02 - a20 - 2.0f * a21 - a22) * 0.25f;
        float mag = sqrtf(gxv * gxv + gyv * gyv + 1e-6f);
        ma[p] = make_float2(mag, orient_deg(gyv, gxv));
    }
    __syncthreads();

    // ---- C: cell-parallel exclusive RMW, wrap slot + adjacent pair ----
    for (int t = tid; t < NCELL; t += 256) {
        int base, y0, x0, ny, nx, bins;
        float invbw;                       // bins / 180
        if (t < 49) {                      // cell=4, bins=8, 4x4 px
            int cy = t / 7, cx = t - cy * 7;
            y0 = cy * 4; x0 = cx * 4; ny = 4; nx = 4;
            bins = 8; invbw = 8.0f / 180.0f;
            base = O4P + t * PB;
        } else if (t < 130) {              // cell=3, bins=9, 3-4 x 3-4 px
            int k = t - 49;
            int cy = k / 9, cx = k - cy * 9;
            y0 = cy * 3; x0 = cx * 3;
            ny = (cy == 8) ? 4 : 3; nx = (cx == 8) ? 4 : 3;
            bins = 9; invbw = 9.0f / 180.0f;
            base = O3P + k * PB;
        } else {                           // cell=2, bins=6, 2x2 px
            int k = t - 130;
            int cy = k / 14, cx = k - cy * 14;
            y0 = cy * 2; x0 = cx * 2; ny = 2; nx = 2;
            bins = 6; invbw = 6.0f / 180.0f;
            base = O2P + k * PB;
        }
        for (int iy = 0; iy < ny; ++iy) {
            int row = (y0 + iy) * 28 + x0;
            for (int ix = 0; ix < nx; ++ix) {
                float2 m = ma[row + ix];
                float tb = m.y * invbw;            // in [0, bins)
                int b0 = (int)tb;
                if (b0 > bins - 1) b0 = bins - 1;  // float-edge guard
                float frac = tb - (float)b0;
                float w1 = m.x * frac;
                float w0 = m.x - w1;
                int a = base + b0;                 // b1==bins -> wrap slot
                float h0 = hist[a];
                float h1 = hist[a + 1];            // ds_read2_b32
                hist[a]     = h0 + w0;
                hist[a + 1] = h1 + w1;             // ds_write2_b32
            }
        }
        hist[base] += hist[base + bins];           // fold wrap slot into bin 0
    }
    __syncthreads();

    // ---- D: per-task L2-hys norm factors (streaming float2 reads) ----
    for (int t = tid; t < NTASK; t += 256) {
        float2 r;
        if (t < 36) {
            int by = t / 6, bx = t - (t / 6) * 6;
            r = norm_task<8>(hist, O4P + (by * 7 + bx) * PB, 7);
        } else if (t < 100) {
            int k = t - 36;
            r = norm_task<9>(hist, O3P + ((k >> 3) * 9 + (k & 7)) * PB, 9);
        } else {
            int k = t - 100;
            int by = k / 13, bx = k - by * 13;
            r = norm_task<6>(hist, O2P + (by * 14 + bx) * PB, 14);
        }
        nrm[t] = r;
    }
    __syncthreads();

    // ---- E: epilogue, coalesced float4 writes ----
    float4* outp = reinterpret_cast<float4*>(out + (size_t)b * FEAT);

    for (int i4 = tid; i4 < NPIX / 4; i4 += 256) {
        float4 v = reinterpret_cast<const float4*>(img)[i4];
        float4 r;
        if (USE_TABLE) {
            const float4* msr4 = reinterpret_cast<const float4*>(msr);
            float4 p0 = msr4[i4 * 2], p1 = msr4[i4 * 2 + 1];
            r.x = (v.x - p0.x) * p0.y;  r.y = (v.y - p0.z) * p0.w;
            r.z = (v.z - p1.x) * p1.y;  r.w = (v.w - p1.z) * p1.w;
        } else {
            int i = i4 * 4;
            r.x = (v.x - fmean[i])     / fstd[i];
            r.y = (v.y - fmean[i + 1]) / fstd[i + 1];
            r.z = (v.z - fmean[i + 2]) / fstd[i + 2];
            r.w = (v.w - fmean[i + 3]) / fstd[i + 3];
        }
        outp[i4] = r;
    }

    for (int t4 = tid; t4 < NHOG / 4; t4 += 256) {
        int i4 = NPIX / 4 + t4;
        int mp[4];
        if (USE_TABLE) {
            int4 m4 = reinterpret_cast<const int4*>(map)[t4];
            mp[0] = m4.x; mp[1] = m4.y; mp[2] = m4.z; mp[3] = m4.w;
        } else {
            #pragma unroll
            for (int e = 0; e < 4; ++e) mp[e] = feat_map(i4 * 4 + e);
        }
        float vv[4];
        #pragma unroll
        for (int e = 0; e < 4; ++e) {
            int task = mp[e] >> 12, h = mp[e] & 4095;
            float2 n = nrm[task];
            vv[e] = fminf(hist[h] * n.x, 0.2f) * n.y;
        }
        float4 r;
        if (USE_TABLE) {
            const float4* msr4 = reinterpret_cast<const float4*>(msr);
            float4 p0 = msr4[i4 * 2], p1 = msr4[i4 * 2 + 1];
            r.x = (vv[0] - p0.x) * p0.y;  r.y = (vv[1] - p0.z) * p0.w;
            r.z = (vv[2] - p1.x) * p1.y;  r.w = (vv[3] - p1.z) * p1.w;
        } else {
            int i = i4 * 4;
            r.x = (vv[0] - fmean[i])     / fstd[i];
            r.y = (vv[1] - fmean[i + 1]) / fstd[i + 1];
            r.z = (vv[2] - fmean[i + 2]) / fstd[i + 2];
            r.w = (vv[3] - fmean[i + 3]) / fstd[i + 3];
        }
        outp[i4] = r;
    }
}

extern "C" void kernel_launch(void* const* d_in, const int* in_sizes, int n_in,
                              void* d_out, int out_size, void* d_ws, size_t ws_size,
                              hipStream_t stream) {
    const float* x     = (const float*)d_in[0];
    const float* fmean = (const float*)d_in[1];
    const float* fstd  = (const float*)d_in[2];
    float* out = (float*)d_out;
    int B = in_sizes[0] / NPIX;

    const size_t msr_bytes = (size_t)FEAT * sizeof(float2);   // 66368
    const size_t map_bytes = (size_t)NHOG * sizeof(int);      // 30048
    if (ws_size >= msr_bytes + map_bytes) {
        float2* msr = (float2*)d_ws;
        int* map = (int*)((char*)d_ws + msr_bytes);
        hipLaunchKernelGGL(setup_kernel, dim3((FEAT + 255) / 256), dim3(256),
                           0, stream, fmean, fstd, msr, map);
        hipLaunchKernelGGL(hog_kernel<true>, dim3(B), dim3(256), 0, stream,
                           x, fmean, fstd, msr, map, out);
    } else {
        hipLaunchKernelGGL(hog_kernel<false>, dim3(B), dim3(256), 0, stream,
                           x, fmean, fstd, nullptr, nullptr, out);
    }
}